// Round 1
// baseline (90.810 us; speedup 1.0000x reference)
//
#include <hip/hip_runtime.h>

#define D        4096
#define NERR     8192
#define ROWCH    64                 // row chunks for partial column sums
#define RPC      (NERR / ROWCH)     // 128 rows per chunk
#define D4       (D / 4)            // 1024 float4 per row

// ---------------- Kernel A: partial column sums of |e| ----------------
// grid = ROWCH * 4 blocks, 256 threads. Each block: 128 rows x 1024 cols.
__global__ void k_colsum_partial(const float4* __restrict__ e4,
                                 float4* __restrict__ part4) {
    const int t     = threadIdx.x;
    const int cb    = blockIdx.x & 3;     // 4 column blocks of 1024 cols
    const int chunk = blockIdx.x >> 2;    // 64 row chunks
    const int col4  = cb * 256 + t;       // float4 column index [0,1024)
    const float4* p = e4 + (size_t)chunk * RPC * D4 + col4;

    float4 acc = make_float4(0.f, 0.f, 0.f, 0.f);
    #pragma unroll 4
    for (int r = 0; r < RPC; ++r) {
        float4 v = p[(size_t)r * D4];
        acc.x += fabsf(v.x);
        acc.y += fabsf(v.y);
        acc.z += fabsf(v.z);
        acc.w += fabsf(v.w);
    }
    part4[chunk * D4 + col4] = acc;
}

// ---------------- Kernel B: reduce partials + per-column transform -----
// grid = D/256 = 16 blocks, 256 threads; one thread per column.
__global__ void k_finalize_cols(const float* __restrict__ part,
                                const float* __restrict__ center,
                                float* __restrict__ out_center,
                                float* __restrict__ col_scale,
                                float* __restrict__ mu_arr) {
    const int col = blockIdx.x * 256 + threadIdx.x;
    float apt = 0.f;
    #pragma unroll 8
    for (int k = 0; k < ROWCH; ++k) apt += part[k * D + col];

    const float c  = center[col];
    const float ub = c + apt;
    const float lb = c - apt;
    const bool cross = (ub > 0.f) && (lb < 0.f);
    const bool act   = (lb >= 0.f);

    const float denom = cross ? (ub - lb) : 1.f;
    const float slope = cross ? (ub / denom) : 0.f;
    const float mu    = cross ? (-slope * lb * 0.5f) : 0.f;

    out_center[col] = act ? c : (slope * c + mu);
    col_scale[col]  = act ? 1.f : slope;
    mu_arr[col]     = mu;
}

// ---------------- Kernel C: top = e * col_scale ------------------------
// grid-stride over NERR*D4 float4 elements.
__global__ void k_scale_top(const float4* __restrict__ e4,
                            const float4* __restrict__ cs4,
                            float4* __restrict__ out4) {
    const int n4     = NERR * D4;                 // 8,388,608
    const int stride = gridDim.x * blockDim.x;
    for (int i = blockIdx.x * blockDim.x + threadIdx.x; i < n4; i += stride) {
        const int c4 = i & (D4 - 1);
        float4 v = e4[i];
        const float4 s = cs4[c4];
        v.x *= s.x; v.y *= s.y; v.z *= s.z; v.w *= s.w;
        out4[i] = v;
    }
}

// ---------------- Kernel D: bottom = diag(mu) --------------------------
// grid-stride over D*D4 float4 elements; zeros except one diag element/row.
__global__ void k_write_bottom(const float* __restrict__ mu_arr,
                               float4* __restrict__ out4) {
    const int n4     = D * D4;                    // 4,194,304
    const int stride = gridDim.x * blockDim.x;
    for (int i = blockIdx.x * blockDim.x + threadIdx.x; i < n4; i += stride) {
        const int row = i >> 10;                  // / D4
        const int j4  = i & (D4 - 1);
        float4 v = make_float4(0.f, 0.f, 0.f, 0.f);
        if (j4 == (row >> 2)) {
            const float m = mu_arr[row];
            switch (row & 3) {
                case 0: v.x = m; break;
                case 1: v.y = m; break;
                case 2: v.z = m; break;
                case 3: v.w = m; break;
            }
        }
        out4[i] = v;
    }
}

extern "C" void kernel_launch(void* const* d_in, const int* in_sizes, int n_in,
                              void* d_out, int out_size, void* d_ws, size_t ws_size,
                              hipStream_t stream) {
    const float* center = (const float*)d_in[0];   // (4096,)
    const float* error  = (const float*)d_in[1];   // (8192, 4096)
    float* out = (float*)d_out;
    float* ws  = (float*)d_ws;

    // ws layout (floats): [partials: ROWCH*D][col_scale: D][mu: D] ~= 1.06 MB
    float* part      = ws;
    float* col_scale = ws + (size_t)ROWCH * D;
    float* mu_arr    = col_scale + D;

    float* out_center = out;                                   // (4096,)
    float* out_top    = out + D;                               // (8192, 4096)
    float* out_bottom = out + (size_t)D + (size_t)NERR * D;    // (4096, 4096)

    k_colsum_partial<<<ROWCH * 4, 256, 0, stream>>>(
        (const float4*)error, (float4*)part);
    k_finalize_cols<<<D / 256, 256, 0, stream>>>(
        part, center, out_center, col_scale, mu_arr);
    k_scale_top<<<2048, 256, 0, stream>>>(
        (const float4*)error, (const float4*)col_scale, (float4*)out_top);
    k_write_bottom<<<2048, 256, 0, stream>>>(
        mu_arr, (float4*)out_bottom);
}